// Round 3
// baseline (147.905 us; speedup 1.0000x reference)
//
#include <hip/hip_runtime.h>

// SNN: 3 LIF layers, B=2097152 rows, widths 2 -> 2 -> 3 -> 2.
// Memory-bound: reads 75.5 MB (x, mem1..3) + writes 75.5 MB -> ~24 us roofline.
//
// Structure: 4 rows per thread so every global access is an aligned float4
// (including the 3-wide mem2: 4 rows x 3 = 12 floats = 3 float4s).
// Kept from the passing round-2 kernel:
//  * __fmul_rn/__fadd_rn in numpy association order (no fma contraction).
//  * All stores bounds-guarded against out_size — no write can leave d_out.

#define BETA 0.90483741803595952f   // exp(-1/10)
#define THR  15.0f

// reset = H(mem_prev - 15); mem = (beta*mem_prev + cur) * (1-reset); spk = H(mem-15)
__device__ __forceinline__ void lif(float cur, float mem_prev, float& nm, float& spk) {
    float base = __fadd_rn(__fmul_rn(BETA, mem_prev), cur);
    nm  = (mem_prev > THR) ? 0.0f : base;
    spk = (nm > THR) ? 1.0f : 0.0f;
}

struct Wts {
    float w1_00, w1_01, w1_10, w1_11;
    float w2_00, w2_01, w2_10, w2_11, w2_20, w2_21;
    float w3_00, w3_01, w3_02, w3_10, w3_11, w3_12;
};

// One row: inputs (x0,x1, m1[2], m2[3], m3[2]) -> outputs (s3[2], m1o[2], m2o[3], m3o[2])
__device__ __forceinline__ void snn_row(const Wts& w,
                                        float x0, float x1,
                                        const float m1[2], const float m2[3], const float m3[2],
                                        float s3[2], float m1o[2], float m2o[3], float m3o[2]) {
    float cur1_0 = __fadd_rn(__fmul_rn(x0, w.w1_00), __fmul_rn(x1, w.w1_01));
    float cur1_1 = __fadd_rn(__fmul_rn(x0, w.w1_10), __fmul_rn(x1, w.w1_11));
    float s1_0, s1_1;
    lif(cur1_0, m1[0], m1o[0], s1_0);
    lif(cur1_1, m1[1], m1o[1], s1_1);

    float cur2_0 = __fadd_rn(__fmul_rn(s1_0, w.w2_00), __fmul_rn(s1_1, w.w2_01));
    float cur2_1 = __fadd_rn(__fmul_rn(s1_0, w.w2_10), __fmul_rn(s1_1, w.w2_11));
    float cur2_2 = __fadd_rn(__fmul_rn(s1_0, w.w2_20), __fmul_rn(s1_1, w.w2_21));
    float s2_0, s2_1, s2_2;
    lif(cur2_0, m2[0], m2o[0], s2_0);
    lif(cur2_1, m2[1], m2o[1], s2_1);
    lif(cur2_2, m2[2], m2o[2], s2_2);

    float cur3_0 = __fadd_rn(__fadd_rn(__fmul_rn(s2_0, w.w3_00), __fmul_rn(s2_1, w.w3_01)),
                             __fmul_rn(s2_2, w.w3_02));
    float cur3_1 = __fadd_rn(__fadd_rn(__fmul_rn(s2_0, w.w3_10), __fmul_rn(s2_1, w.w3_11)),
                             __fmul_rn(s2_2, w.w3_12));
    lif(cur3_0, m3[0], m3o[0], s3[0]);
    lif(cur3_1, m3[1], m3o[1], s3[1]);
}

__global__ __launch_bounds__(256) void snn_kernel(
    const float* __restrict__ x,
    const float* __restrict__ mem1,
    const float* __restrict__ mem2,
    const float* __restrict__ mem3,
    const float* __restrict__ W1, const float* __restrict__ W2, const float* __restrict__ W3,
    float* __restrict__ out,        // spk3[2B] | mem1[2B] | mem2[3B] | mem3[2B]
    int B, long long out_n)
{
    const long long t = (long long)blockIdx.x * blockDim.x + threadIdx.x;
    const long long r0 = t * 4;
    if (r0 >= B) return;

    Wts w;
    w.w1_00 = W1[0]; w.w1_01 = W1[1]; w.w1_10 = W1[2]; w.w1_11 = W1[3];
    w.w2_00 = W2[0]; w.w2_01 = W2[1]; w.w2_10 = W2[2];
    w.w2_11 = W2[3]; w.w2_20 = W2[4]; w.w2_21 = W2[5];
    w.w3_00 = W3[0]; w.w3_01 = W3[1]; w.w3_02 = W3[2];
    w.w3_10 = W3[3]; w.w3_11 = W3[4]; w.w3_12 = W3[5];

    const long long Bl = B;
    const long long out_n4 = out_n >> 2;   // float4 capacity of d_out

    if (r0 + 3 < Bl) {
        // ---- fast path: 4 full rows, everything float4 ----
        const float4* x4  = (const float4*)x;
        const float4* m14 = (const float4*)mem1;
        const float4* m24 = (const float4*)mem2;
        const float4* m34 = (const float4*)mem3;

        float4 xv0 = x4[t * 2 + 0], xv1 = x4[t * 2 + 1];
        float4 a0  = m14[t * 2 + 0], a1 = m14[t * 2 + 1];
        float4 b0  = m24[t * 3 + 0], b1 = m24[t * 3 + 1], b2 = m24[t * 3 + 2];
        float4 c0  = m34[t * 2 + 0], c1 = m34[t * 2 + 1];

        float xr[4][2] = {{xv0.x, xv0.y}, {xv0.z, xv0.w}, {xv1.x, xv1.y}, {xv1.z, xv1.w}};
        float m1[4][2] = {{a0.x, a0.y}, {a0.z, a0.w}, {a1.x, a1.y}, {a1.z, a1.w}};
        float m2[4][3] = {{b0.x, b0.y, b0.z}, {b0.w, b1.x, b1.y},
                          {b1.z, b1.w, b2.x}, {b2.y, b2.z, b2.w}};
        float m3[4][2] = {{c0.x, c0.y}, {c0.z, c0.w}, {c1.x, c1.y}, {c1.z, c1.w}};

        float s3o[4][2], m1o[4][2], m2o[4][3], m3o[4][2];
#pragma unroll
        for (int r = 0; r < 4; ++r)
            snn_row(w, xr[r][0], xr[r][1], m1[r], m2[r], m3[r],
                    s3o[r], m1o[r], m2o[r], m3o[r]);

        float4* o4 = (float4*)out;
        long long f;
        // spk3 @ float4-offset 0
        f = t * 2;
        if (f + 1 < out_n4) {
            o4[f + 0] = make_float4(s3o[0][0], s3o[0][1], s3o[1][0], s3o[1][1]);
            o4[f + 1] = make_float4(s3o[2][0], s3o[2][1], s3o[3][0], s3o[3][1]);
        }
        // mem1 @ float offset 2B (B divisible by 2 -> float4 offset B/2)
        f = (2 * Bl >> 2) + t * 2;
        if (f + 1 < out_n4) {
            o4[f + 0] = make_float4(m1o[0][0], m1o[0][1], m1o[1][0], m1o[1][1]);
            o4[f + 1] = make_float4(m1o[2][0], m1o[2][1], m1o[3][0], m1o[3][1]);
        }
        // mem2 @ float offset 4B
        f = (4 * Bl >> 2) + t * 3;
        if (f + 2 < out_n4) {
            o4[f + 0] = make_float4(m2o[0][0], m2o[0][1], m2o[0][2], m2o[1][0]);
            o4[f + 1] = make_float4(m2o[1][1], m2o[1][2], m2o[2][0], m2o[2][1]);
            o4[f + 2] = make_float4(m2o[2][2], m2o[3][0], m2o[3][1], m2o[3][2]);
        }
        // mem3 @ float offset 7B  (7B may not be /4; guard alignment via float path if so)
        if (((7 * Bl) & 3) == 0) {
            f = (7 * Bl >> 2) + t * 2;
            if (f + 1 < out_n4) {
                o4[f + 0] = make_float4(m3o[0][0], m3o[0][1], m3o[1][0], m3o[1][1]);
                o4[f + 1] = make_float4(m3o[2][0], m3o[2][1], m3o[3][0], m3o[3][1]);
            }
        } else {
            long long i = 7 * Bl + 2 * r0;
            if (i + 7 < out_n) {
#pragma unroll
                for (int r = 0; r < 4; ++r) { out[i + 2*r] = m3o[r][0]; out[i + 2*r + 1] = m3o[r][1]; }
            }
        }
    } else {
        // ---- tail: scalar per row ----
        for (long long rr = r0; rr < Bl; ++rr) {
            float m1[2] = {mem1[2*rr], mem1[2*rr+1]};
            float m2[3] = {mem2[3*rr], mem2[3*rr+1], mem2[3*rr+2]};
            float m3[2] = {mem3[2*rr], mem3[2*rr+1]};
            float s3[2], m1o[2], m2o[3], m3o[2];
            snn_row(w, x[2*rr], x[2*rr+1], m1, m2, m3, s3, m1o, m2o, m3o);
            long long i;
            i = 2*rr;           if (i+1 < out_n) { out[i] = s3[0];  out[i+1] = s3[1]; }
            i = 2*Bl + 2*rr;    if (i+1 < out_n) { out[i] = m1o[0]; out[i+1] = m1o[1]; }
            i = 4*Bl + 3*rr;    if (i+2 < out_n) { out[i] = m2o[0]; out[i+1] = m2o[1]; out[i+2] = m2o[2]; }
            i = 7*Bl + 2*rr;    if (i+1 < out_n) { out[i] = m3o[0]; out[i+1] = m3o[1]; }
        }
    }
}

extern "C" void kernel_launch(void* const* d_in, const int* in_sizes, int n_in,
                              void* d_out, int out_size, void* d_ws, size_t ws_size,
                              hipStream_t stream) {
    const float* x    = (const float*)d_in[0];
    const float* mem1 = (const float*)d_in[1];
    const float* mem2 = (const float*)d_in[2];
    const float* mem3 = (const float*)d_in[3];
    const float* W1   = (const float*)d_in[4];
    const float* W2   = (const float*)d_in[5];
    const float* W3   = (const float*)d_in[6];
    float* out        = (float*)d_out;

    const int B = in_sizes[0] / 2;                 // x is [B,2]
    const int threads = (B + 3) / 4;               // 4 rows per thread
    const int block = 256;
    const int grid = (threads + block - 1) / block;

    snn_kernel<<<grid, block, 0, stream>>>(x, mem1, mem2, mem3, W1, W2, W3,
                                           out, B, (long long)out_size);
}